// Round 4
// baseline (109.463 us; speedup 1.0000x reference)
//
#include <hip/hip_runtime.h>

// LIF scan, B=65536 x L=400. Round 4: wave specialization + nt stores.
// Structural cap: 1 row/thread -> 65536 compute lanes = 1 wave/SIMD. So we
// ADD a second wave per SIMD that does nothing but store:
//   block = 128 threads = {wave0: compute, wave1: store}, grid = 1024
//   -> 2048 waves = 2 waves/SIMD. Compute wave: direct global->reg loads
//   (double-buffered), pure-VALU scan, bit-packed spikes (80b = 3 u32) into
//   double-buffered LDS (1.5KB). Store wave: unpack -> full-line float4
//   NONTEMPORAL stores (output stream stops evicting the input from L3;
//   round-3 FETCH=58MB showed write-allocate thrash).
// One __syncthreads per chunk; double-buffered bits give a 1-chunk lag so
// store drain overlaps the next chunk's scan.
// div20 = Markstein 2-fma correctly-rounded v/20 (validated rounds 3: absmax
// 2.0 vs threshold 7.2).

#define L_LEN 400
#define TC 80                 // timesteps per chunk (320B/row = 5 full lines)
#define NC 5
#define F4C 20                // float4 per chunk per row
#define BIG 0x7fffffff

typedef float f4 __attribute__((ext_vector_type(4)));

__device__ __forceinline__ float div20(float v) {
    const float c = 0.05f;           // RN(1/20)
    float q = v * c;
    float r = fmaf(-20.0f, q, v);    // exact residual
    return fmaf(r, c, q);            // correctly-rounded v/20
}

__device__ __forceinline__ void load_chunk(const float* __restrict__ I, int row,
                                           int c, f4* regs) {
#pragma unroll
    for (int k = 0; k < F4C; ++k)
        regs[k] = *reinterpret_cast<const f4*>(
            I + (size_t)row * L_LEN + c * TC + k * 4);
}

struct ScanState {
    float v;
    int num;    // sum t*spike (absolute t), exact int
    int cnt;
    int first;  // BIG if none
};

__device__ __forceinline__ void scan_chunk(const f4* in, int cbase,
                                           ScanState& st, unsigned* bw) {
    unsigned b0 = 0, b1 = 0, b2 = 0;
    int numL = 0;
#pragma unroll
    for (int k = 0; k < F4C; ++k) {
#pragma unroll
        for (int m = 0; m < 4; ++m) {
            const int tl = k * 4 + m;               // compile-time 0..79
            float x = in[k][m];
            // reference association: v = v + ((-v/20) + x)
            float d  = x - div20(st.v);
            float vn = st.v + d;
            bool fire = vn >= 1.0f;
            numL = fire ? numL + tl : numL;
            if (tl < 32)      b0 |= fire ? (1u << tl) : 0u;
            else if (tl < 64) b1 |= fire ? (1u << (tl - 32)) : 0u;
            else              b2 |= fire ? (1u << (tl - 64)) : 0u;
            st.v = fire ? 0.0f : vn;
        }
    }
    int cntC = __builtin_popcount(b0) + __builtin_popcount(b1) +
               __builtin_popcount(b2);
    int fl = b0 ? __builtin_ctz(b0)
           : (b1 ? 32 + __builtin_ctz(b1)
           : (b2 ? 64 + __builtin_ctz(b2) : -1));
    st.num += numL + cbase * cntC;
    st.cnt += cntC;
    st.first = min(st.first, fl >= 0 ? cbase + fl : BIG);
    bw[0] = b0; bw[1] = b1; bw[2] = b2;
}

__global__ __launch_bounds__(128, 2) void lif_kernel(const float* __restrict__ I,
                                                     float* __restrict__ spikes,
                                                     float* __restrict__ hard_lat,
                                                     float* __restrict__ soft_lat) {
    __shared__ unsigned bits[2][64][3];   // double-buffered packed spikes
    const int lane = threadIdx.x & 63;
    const int wid  = threadIdx.x >> 6;    // 0 = compute, 1 = store (wave-uniform)
    const int R0 = blockIdx.x * 64;
    const int row = R0 + lane;

    f4 A[F4C], Bb[F4C];
    ScanState st;
    st.v = 0.0f; st.num = 0; st.cnt = 0; st.first = BIG;

    if (wid == 0) {
        load_chunk(I, row, 0, A);
        load_chunk(I, row, 1, Bb);
    }

    for (int c = 0; c < NC; ++c) {
        if (wid == 0) {
            unsigned bw[3];
            if ((c & 1) == 0) {
                scan_chunk(A, c * TC, st, bw);
                if (c + 2 < NC) load_chunk(I, row, c + 2, A);
            } else {
                scan_chunk(Bb, c * TC, st, bw);
                if (c + 2 < NC) load_chunk(I, row, c + 2, Bb);
            }
            bits[c & 1][lane][0] = bw[0];
            bits[c & 1][lane][1] = bw[1];
            bits[c & 1][lane][2] = bw[2];
        }
        __syncthreads();   // bits[c&1] visible; storer's prev-chunk reads drained
        if (wid == 1) {
#pragma unroll
            for (int i = 0; i < F4C; ++i) {
                int flat = i * 64 + lane;       // 0..1279
                int rl = flat / F4C;            // row within block's 64
                int k  = flat % F4C;            // float4 index 0..19
                unsigned w = bits[c & 1][rl][k >> 3];
                int sh = (4 * k) & 31;          // nibble offset (never straddles)
                f4 s;
                s.x = (float)((w >> (sh + 0)) & 1u);
                s.y = (float)((w >> (sh + 1)) & 1u);
                s.z = (float)((w >> (sh + 2)) & 1u);
                s.w = (float)((w >> (sh + 3)) & 1u);
                __builtin_nontemporal_store(s, reinterpret_cast<f4*>(
                    spikes + (size_t)(R0 + rl) * L_LEN + c * TC + k * 4));
            }
        }
    }

    if (wid == 0) {
        hard_lat[row] = (float)(st.first == BIG ? 0 : st.first);
        soft_lat[row] = (float)st.num / ((float)st.cnt + 1e-6f);
    }
}

extern "C" void kernel_launch(void* const* d_in, const int* in_sizes, int n_in,
                              void* d_out, int out_size, void* d_ws, size_t ws_size,
                              hipStream_t stream) {
    const float* I = (const float*)d_in[0];
    int B = in_sizes[0] / L_LEN;  // 65536

    float* spk = (float*)d_out;
    float* hard = spk + (size_t)B * L_LEN;
    float* soft = hard + B;

    dim3 block(128);
    dim3 grid(B / 64);  // 1024 blocks, 2 waves each
    hipLaunchKernelGGL(lif_kernel, grid, block, 0, stream, I, spk, hard, soft);
}

// Round 5
// 48.006 us; speedup vs baseline: 2.2802x; 2.2802x over previous
//
#include <hip/hip_runtime.h>

// LIF scan, B=65536 x L=400. Round 5: two-kernel split.
// Round-4 lesson (counters): nontemporal stores = 2.4x write amplification
// (WRITE 106->252MB) — reverted; plain stores + L2 merge are optimal.
// Structural fact: scan is sequential in t -> only 65536 threads = 1 wave/SIMD.
// So don't make that kernel drain 106MB of stores:
//   K1 lif_scan:   1024 waves. Triple-buffered direct-to-reg loads, pure-reg
//                  scan, spikes bit-packed to 13 u32/row, stored as ONE 64B
//                  line at the head of each output row (4.2MB writes total).
//                  hard/soft latencies computed here too.
//   K2 lif_expand: 1024 blocks x 256 threads (4 waves/SIMD). Each block owns
//                  64 rows: reads its rows' 13 words (block-exclusive ->
//                  no cross-block race), __syncthreads, expands bits->f32,
//                  fully-coalesced float4 stores of the 105MB spike matrix.
// div20 = Markstein 2-fma correctly-rounded v/20 (validated r3/r4: absmax 2.0
// vs threshold 7.2).

#define L_LEN 400
#define TC 80
#define NC 5
#define F4C 20                // float4 per chunk per row
#define RPB 64                // rows per expand-block (25*RPB % 256 == 0 -> 64)
#define BIG 0x7fffffff

typedef float f4 __attribute__((ext_vector_type(4)));

__device__ __forceinline__ float div20(float v) {
    const float c = 0.05f;           // RN(1/20)
    float q = v * c;
    float r = fmaf(-20.0f, q, v);    // exact residual
    return fmaf(r, c, q);            // correctly-rounded v/20
}

__device__ __forceinline__ void load_chunk(const float* __restrict__ I, int row,
                                           int c, f4* regs) {
#pragma unroll
    for (int k = 0; k < F4C; ++k)
        regs[k] = *reinterpret_cast<const f4*>(
            I + (size_t)row * L_LEN + c * TC + k * 4);
}

struct ScanState {
    float v;
    int num;    // sum t*spike (absolute t), exact int (max 79800)
    int cnt;
    int first;  // BIG if none
};

__device__ __forceinline__ void scan_chunk(const f4* in, int cbase,
                                           ScanState& st, unsigned* bw) {
    unsigned b0 = 0, b1 = 0, b2 = 0;
    int numL = 0;
#pragma unroll
    for (int k = 0; k < F4C; ++k) {
#pragma unroll
        for (int m = 0; m < 4; ++m) {
            const int tl = k * 4 + m;               // compile-time 0..79
            float x = in[k][m];
            // reference association: v = v + ((-v/20) + x)
            float d  = x - div20(st.v);
            float vn = st.v + d;
            bool fire = vn >= 1.0f;
            numL = fire ? numL + tl : numL;
            if (tl < 32)      b0 |= fire ? (1u << tl) : 0u;
            else if (tl < 64) b1 |= fire ? (1u << (tl - 32)) : 0u;
            else              b2 |= fire ? (1u << (tl - 64)) : 0u;
            st.v = fire ? 0.0f : vn;
        }
    }
    int cntC = __builtin_popcount(b0) + __builtin_popcount(b1) +
               __builtin_popcount(b2);
    int fl = b0 ? __builtin_ctz(b0)
           : (b1 ? 32 + __builtin_ctz(b1)
           : (b2 ? 64 + __builtin_ctz(b2) : -1));
    st.num += numL + cbase * cntC;
    st.cnt += cntC;
    st.first = min(st.first, fl >= 0 ? cbase + fl : BIG);
    bw[0] = b0; bw[1] = b1; bw[2] = b2;
}

__global__ __launch_bounds__(64, 1) void lif_scan_kernel(const float* __restrict__ I,
                                                         float* __restrict__ out,
                                                         float* __restrict__ hard_lat,
                                                         float* __restrict__ soft_lat) {
    const int row = blockIdx.x * 64 + threadIdx.x;

    f4 A[F4C], B[F4C], C[F4C];
    load_chunk(I, row, 0, A);     // triple buffer: 2 chunks always in flight
    load_chunk(I, row, 1, B);
    load_chunk(I, row, 2, C);

    ScanState st;
    st.v = 0.0f; st.num = 0; st.cnt = 0; st.first = BIG;

    unsigned w[16];
#pragma unroll
    for (int i = 0; i < 16; ++i) w[i] = 0;
    unsigned bw[3];

    // chunk 0: bits 0..79 -> w0,w1,w2(lo16)
    scan_chunk(A, 0, st, bw);
    w[0] = bw[0]; w[1] = bw[1]; w[2] = bw[2];
    load_chunk(I, row, 3, A);
    // chunk 1: bits 80..159 -> w2(hi16),w3,w4
    scan_chunk(B, 80, st, bw);
    w[2] |= bw[0] << 16; w[3] = (bw[0] >> 16) | (bw[1] << 16);
    w[4] = (bw[1] >> 16) | (bw[2] << 16);
    load_chunk(I, row, 4, B);
    // chunk 2: bits 160..239 -> w5,w6,w7(lo16)
    scan_chunk(C, 160, st, bw);
    w[5] = bw[0]; w[6] = bw[1]; w[7] = bw[2];
    // chunk 3: bits 240..319 -> w7(hi16),w8,w9
    scan_chunk(A, 240, st, bw);
    w[7] |= bw[0] << 16; w[8] = (bw[0] >> 16) | (bw[1] << 16);
    w[9] = (bw[1] >> 16) | (bw[2] << 16);
    // chunk 4: bits 320..399 -> w10,w11,w12(lo16)
    scan_chunk(B, 320, st, bw);
    w[10] = bw[0]; w[11] = bw[1]; w[12] = bw[2];

    // store 64B (one full line) of packed bits at the head of this row's output
    float* dst = out + (size_t)row * L_LEN;
#pragma unroll
    for (int q = 0; q < 4; ++q) {
        f4 s;
        s.x = __uint_as_float(w[4 * q + 0]);
        s.y = __uint_as_float(w[4 * q + 1]);
        s.z = __uint_as_float(w[4 * q + 2]);
        s.w = __uint_as_float(w[4 * q + 3]);
        *reinterpret_cast<f4*>(dst + 4 * q) = s;
    }

    hard_lat[row] = (float)(st.first == BIG ? 0 : st.first);
    soft_lat[row] = (float)st.num / ((float)st.cnt + 1e-6f);
}

__global__ __launch_bounds__(256) void lif_expand_kernel(float* __restrict__ spikes) {
    __shared__ unsigned ldsw[RPB * 13];   // 3328B
    const int tid = threadIdx.x;
    const int R0 = blockIdx.x * RPB;

    // gather this block's rows' bit-words (block-exclusive region)
#pragma unroll
    for (int i = 0; i < 4; ++i) {
        int idx = tid + 256 * i;
        if (idx < RPB * 13) {
            int r = idx / 13, wi = idx % 13;
            ldsw[idx] = __float_as_uint(spikes[(size_t)(R0 + r) * L_LEN + wi]);
        }
    }
    __syncthreads();

    // expand: 64 rows * 100 float4 = 6400 f4 = 25 per thread, coalesced stores
#pragma unroll
    for (int i = 0; i < 25; ++i) {
        int flat = i * 256 + tid;           // 0..6399 == lr*100 + k
        int lr = flat / 100;
        int k  = flat % 100;
        unsigned w = ldsw[lr * 13 + (k >> 3)];
        int sh = (4 * k) & 31;              // nibble never straddles a word
        f4 s;
        s.x = (float)((w >> (sh + 0)) & 1u);
        s.y = (float)((w >> (sh + 1)) & 1u);
        s.z = (float)((w >> (sh + 2)) & 1u);
        s.w = (float)((w >> (sh + 3)) & 1u);
        *reinterpret_cast<f4*>(spikes + (size_t)R0 * L_LEN + (size_t)flat * 4) = s;
    }
}

extern "C" void kernel_launch(void* const* d_in, const int* in_sizes, int n_in,
                              void* d_out, int out_size, void* d_ws, size_t ws_size,
                              hipStream_t stream) {
    const float* I = (const float*)d_in[0];
    int B = in_sizes[0] / L_LEN;  // 65536

    float* spk = (float*)d_out;
    float* hard = spk + (size_t)B * L_LEN;
    float* soft = hard + B;

    hipLaunchKernelGGL(lif_scan_kernel, dim3(B / 64), dim3(64), 0, stream,
                       I, spk, hard, soft);
    hipLaunchKernelGGL(lif_expand_kernel, dim3(B / RPB), dim3(256), 0, stream,
                       spk);
}